// Round 11
// baseline (97.097 us; speedup 1.0000x reference)
//
#include <hip/hip_runtime.h>
#include <hip/hip_bf16.h>
#include <stdint.h>

#define N_NODES 100000
#define DEG 16
#define IN_F 128
#define OUT_F 64
#define ALPHA 0.2f

typedef __attribute__((ext_vector_type(8))) short short8;
typedef __attribute__((ext_vector_type(4))) float f32x4;
typedef __attribute__((ext_vector_type(2))) float f32x2;
typedef __attribute__((ext_vector_type(4))) int i32x4;
typedef __attribute__((ext_vector_type(4))) unsigned int u32x4;

static __device__ __forceinline__ unsigned int pack2bf(float lo, float hi) {
    __hip_bfloat162 h = __float22bfloat162_rn(make_float2(lo, hi));
    unsigned int u; __builtin_memcpy(&u, &h, 4); return u;
}
static __device__ __forceinline__ unsigned short f2bf(float f) {
    __hip_bfloat16 h = __float2bfloat16(f);   // RTNE
    unsigned short u; __builtin_memcpy(&u, &h, 2); return u;
}

// Prep: w -> bf16 (R9-proven; faster than in-kernel conversion, R10 regression).
__global__ __launch_bounds__(256) void prep_kernel(
    const float* __restrict__ w, unsigned short* __restrict__ wb)
{
    int idx = blockIdx.x * 256 + threadIdx.x;
    if (idx < OUT_F * IN_F) wb[idx] = f2bf(w[idx]);
}

// Kernel 1: feat = x @ w^T via bf16 MFMA; a1 (+both biases) and a2n from f32
// accumulators. feat stored QUARTER-BLOCKED: featq[q][node][16 bf16] -- four
// 3.2 MB tables, each fitting a per-XCD L2, so the agg passes gather L2-hot.
// LDS bounce XOR-swizzled by row so the quarter-column read is 8-way not 32-way.
__global__ __launch_bounds__(256) void gat_feat_kernel(
    const float* __restrict__ x, const unsigned short* __restrict__ wb,
    const float* __restrict__ a1w, const float* __restrict__ a1bp,
    const float* __restrict__ a2w, const float* __restrict__ a2bp,
    unsigned short* __restrict__ featq, float* __restrict__ a1,
    float* __restrict__ a2n)
{
    __shared__ __align__(16) unsigned short lds[4][32][64]; // per-wave store-bounce tile
    const int wid  = threadIdx.x >> 6;
    const int lane = threadIdx.x & 63;
    const int r = lane & 15;   // A row / B col within 16-tile
    const int g = lane >> 4;   // k-group (8 contiguous k per group)
    const int base = (blockIdx.x * 4 + wid) * 32;
    if (base >= N_NODES) return;   // N % 32 == 0: active waves always full

    short8 bfrag[4][4];
    #pragma unroll
    for (int ft = 0; ft < 4; ++ft)
        #pragma unroll
        for (int ks = 0; ks < 4; ++ks)
            bfrag[ft][ks] = *(const short8*)(wb + (ft * 16 + r) * IN_F + ks * 32 + g * 8);

    f32x4 acc[2][4];
    #pragma unroll
    for (int mt = 0; mt < 2; ++mt)
        #pragma unroll
        for (int ft = 0; ft < 4; ++ft) acc[mt][ft] = (f32x4){0.f, 0.f, 0.f, 0.f};

    #pragma unroll
    for (int mt = 0; mt < 2; ++mt) {
        const float* xrow = x + (size_t)(base + mt * 16 + r) * IN_F;
        #pragma unroll
        for (int ks = 0; ks < 4; ++ks) {
            const float* xp = xrow + ks * 32 + g * 8;
            f32x4 x0 = *(const f32x4*)(xp);
            f32x4 x1 = *(const f32x4*)(xp + 4);
            u32x4 au;
            au[0] = pack2bf(x0[0], x0[1]);
            au[1] = pack2bf(x0[2], x0[3]);
            au[2] = pack2bf(x1[0], x1[1]);
            au[3] = pack2bf(x1[2], x1[3]);
            short8 af; __builtin_memcpy(&af, &au, 16);
            #pragma unroll
            for (int ft = 0; ft < 4; ++ft)
                acc[mt][ft] = __builtin_amdgcn_mfma_f32_16x16x32_bf16(af, bfrag[ft][ks], acc[mt][ft], 0, 0, 0);
        }
    }
    // C/D layout (HW-verified): col = lane&15 -> feature ft*16+r; row = g*4+reg -> node mt*16+g*4+reg

    // a1 = feat@a1w + (b1+b2), a2n = feat@a2w  (agg: z = a1[i] + a2n[d])
    float w1v[4], w2v[4];
    #pragma unroll
    for (int ft = 0; ft < 4; ++ft) { w1v[ft] = a1w[ft * 16 + r]; w2v[ft] = a2w[ft * 16 + r]; }
    float p1[2][4] = {{0.f,0.f,0.f,0.f},{0.f,0.f,0.f,0.f}};
    float p2[2][4] = {{0.f,0.f,0.f,0.f},{0.f,0.f,0.f,0.f}};
    #pragma unroll
    for (int mt = 0; mt < 2; ++mt)
        #pragma unroll
        for (int ft = 0; ft < 4; ++ft)
            #pragma unroll
            for (int reg = 0; reg < 4; ++reg) {
                p1[mt][reg] += acc[mt][ft][reg] * w1v[ft];
                p2[mt][reg] += acc[mt][ft][reg] * w2v[ft];
            }
    #pragma unroll
    for (int m = 1; m <= 8; m <<= 1)
        #pragma unroll
        for (int mt = 0; mt < 2; ++mt)
            #pragma unroll
            for (int reg = 0; reg < 4; ++reg) {
                p1[mt][reg] += __shfl_xor(p1[mt][reg], m, 64);
                p2[mt][reg] += __shfl_xor(p2[mt][reg], m, 64);
            }
    if (r == 0) {
        float b12 = a1bp[0] + a2bp[0];
        #pragma unroll
        for (int mt = 0; mt < 2; ++mt)
            #pragma unroll
            for (int reg = 0; reg < 4; ++reg) {
                a1[base + mt * 16 + g * 4 + reg]  = p1[mt][reg] + b12;
                a2n[base + mt * 16 + g * 4 + reg] = p2[mt][reg];
            }
    }

    // feat -> bf16 -> LDS (phys ushort col = col ^ (reg<<4), reg = row&3)
    #pragma unroll
    for (int mt = 0; mt < 2; ++mt)
        #pragma unroll
        for (int ft = 0; ft < 4; ++ft)
            #pragma unroll
            for (int reg = 0; reg < 4; ++reg)
                lds[wid][mt * 16 + g * 4 + reg][(ft * 16 + r) ^ (reg << 4)] = f2bf(acc[mt][ft][reg]);
    // quarter-blocked store: per q, all 64 lanes write 1 KB contiguous (32 nodes x 32 B)
    const char* lsrc = (const char*)(&lds[wid][0][0]);
    const int row  = lane >> 1;     // 0..31
    const int half = lane & 1;      // 16B half of the 32B quarter-row
    #pragma unroll
    for (int q = 0; q < 4; ++q) {
        i32x4 v = *(const i32x4*)(lsrc + row * 128 + ((q * 32 + half * 16) ^ ((row & 3) << 5)));
        *(i32x4*)((char*)featq + (size_t)(q * N_NODES + base + row) * 32 + half * 16) = v;
    }
}

#define BFLO(w_) __uint_as_float((w_) << 16)
#define BFHI(w_) __uint_as_float((w_) & 0xffff0000u)

// Kernel 2 (x4 passes): gather-aggregate over feature quarter Q from a 3.2 MB
// L2-resident table. One 8-lane group per node; lane l owns edges l and l+8 for
// scores, and dword l of the 32 B quarter-row for gathers. Normalization folded
// into scores (no final divide). All 16 gathers named regs, issued up front.
template<int Q>
__global__ __launch_bounds__(256) void gat_agg_pass(
    const int* __restrict__ dst, const unsigned short* __restrict__ featq,
    const float* __restrict__ a1, const float* __restrict__ a2n,
    const float* __restrict__ bias, float* __restrict__ out)
{
    const int wid  = threadIdx.x >> 6;
    const int lane = threadIdx.x & 63;
    const int l  = lane & 7;
    const int g8 = lane & 56;                         // group base within wave
    const int i = (blockIdx.x * 4 + wid) * 8 + (lane >> 3);   // N % 32 == 0: exact

    const int dA = dst[i * DEG + l];
    const int dB = dst[i * DEG + 8 + l];

    // fire all 16 quarter-row gathers up front (edge l / l+8 of each group)
#define GATH(t) \
    const int deA##t = __shfl(dA, g8 + (t), 64); \
    const int deB##t = __shfl(dB, g8 + (t), 64); \
    const unsigned uA##t = *(const unsigned*)(featq + (size_t)(Q * N_NODES + deA##t) * 16 + l * 2); \
    const unsigned uB##t = *(const unsigned*)(featq + (size_t)(Q * N_NODES + deB##t) * 16 + l * 2);
    GATH(0) GATH(1) GATH(2) GATH(3) GATH(4) GATH(5) GATH(6) GATH(7)
#undef GATH

    // scores while gathers fly: one exp per owned edge; a1/a2n are L2-resident
    const float a1i = a1[i];
    const float zA = a1i + a2n[dA];
    const float zB = a1i + a2n[dB];
    const float sA = __expf(fmaxf(zA, ALPHA * zA));
    const float sB = __expf(fmaxf(zB, ALPHA * zB));
    float ssum = sA + sB;
    ssum += __shfl_xor(ssum, 1, 64);
    ssum += __shfl_xor(ssum, 2, 64);
    ssum += __shfl_xor(ssum, 4, 64);
    const float inv = 1.0f / ssum;
    const float nA = sA * inv, nB = sB * inv;         // normalized scores

#define SE(t) \
    const float seA##t = __shfl(nA, g8 + (t), 64); \
    const float seB##t = __shfl(nB, g8 + (t), 64);
    SE(0) SE(1) SE(2) SE(3) SE(4) SE(5) SE(6) SE(7)
#undef SE

    float acc0 = 0.f, acc1 = 0.f;
#define EDGE(t) \
    acc0 += seA##t * BFLO(uA##t) + seB##t * BFLO(uB##t); \
    acc1 += seA##t * BFHI(uA##t) + seB##t * BFHI(uB##t);
    EDGE(0) EDGE(1) EDGE(2) EDGE(3) EDGE(4) EDGE(5) EDGE(6) EDGE(7)
#undef EDGE

    const int fo = Q * 16 + l * 2;
    const f32x2 bv = *(const f32x2*)(bias + fo);
    f32x2 o; o[0] = acc0 + bv[0]; o[1] = acc1 + bv[1];
    __builtin_nontemporal_store(o, (f32x2*)(out + (unsigned)i * OUT_F + fo));
}

extern "C" void kernel_launch(void* const* d_in, const int* in_sizes, int n_in,
                              void* d_out, int out_size, void* d_ws, size_t ws_size,
                              hipStream_t stream) {
    (void)in_sizes; (void)n_in; (void)out_size; (void)ws_size;
    const float* x    = (const float*)d_in[0];
    const int*   edges= (const int*)d_in[1];   // [2, E] int32, row0=src, row1=dst
    const float* w    = (const float*)d_in[2];
    const float* a1w  = (const float*)d_in[3];
    const float* a1b  = (const float*)d_in[4];
    const float* a2w  = (const float*)d_in[5];
    const float* a2b  = (const float*)d_in[6];
    const float* bias = (const float*)d_in[7];
    float* out = (float*)d_out;

    // ws layout (16B-aligned): featq (4 x 3.2 MB quarter tables) | a1 | a2n | wb
    unsigned short* featq = (unsigned short*)d_ws;                       // N*64 bf16 = 12.8 MB
    float* a1  = (float*)((char*)d_ws + (size_t)N_NODES * OUT_F * 2);
    float* a2n = a1 + N_NODES;
    unsigned short* wb = (unsigned short*)(a2n + N_NODES);

    const int* dst = edges + (size_t)N_NODES * DEG; // edges[1]

    prep_kernel<<<dim3((OUT_F * IN_F + 255) / 256), dim3(256), 0, stream>>>(w, wb);
    gat_feat_kernel<<<dim3((N_NODES + 127) / 128), dim3(256), 0, stream>>>(
        x, wb, a1w, a1b, a2w, a2b, featq, a1, a2n);
    gat_agg_pass<0><<<dim3(N_NODES / 32), dim3(256), 0, stream>>>(dst, featq, a1, a2n, bias, out);
    gat_agg_pass<1><<<dim3(N_NODES / 32), dim3(256), 0, stream>>>(dst, featq, a1, a2n, bias, out);
    gat_agg_pass<2><<<dim3(N_NODES / 32), dim3(256), 0, stream>>>(dst, featq, a1, a2n, bias, out);
    gat_agg_pass<3><<<dim3(N_NODES / 32), dim3(256), 0, stream>>>(dst, featq, a1, a2n, bias, out);
}